// Round 1
// baseline (2139.684 us; speedup 1.0000x reference)
//
#include <hip/hip_runtime.h>
#include <hip/hip_bf16.h>

typedef float  f32x4  __attribute__((ext_vector_type(4)));
typedef __bf16 bf16x8 __attribute__((ext_vector_type(8)));
typedef unsigned short u16x8 __attribute__((ext_vector_type(8)));

#define NN 16384

__device__ inline bf16x8 cvt_bf16x8(f32x4 a, f32x4 b) {
    bf16x8 r;
    r[0] = (__bf16)a[0]; r[1] = (__bf16)a[1]; r[2] = (__bf16)a[2]; r[3] = (__bf16)a[3];
    r[4] = (__bf16)b[0]; r[5] = (__bf16)b[1]; r[6] = (__bf16)b[2]; r[7] = (__bf16)b[3];
    return r;
}

// ---------------------------------------------------------------------------
// Tt = bf16((H @ W))^T  : H [NN, FIN] f32, W [FIN, FOUT] f32 -> Tt [FOUT, NN] bf16
// grid: NN/64 blocks of 256 threads. Each block handles 64 rows of H.
// ---------------------------------------------------------------------------
template<int FIN, int FOUT>
__global__ __launch_bounds__(256) void xw_t_kernel(
    const float* __restrict__ H, const float* __restrict__ W,
    unsigned short* __restrict__ Tt)
{
    __shared__ float sh[64][FIN + 1];
    const int n0 = blockIdx.x * 64;
    // cooperative coalesced load of 64 rows
    for (int i = threadIdx.x; i < 64 * FIN; i += 256) {
        sh[i / FIN][i % FIN] = H[(size_t)n0 * FIN + i];
    }
    __syncthreads();
    const int nl = threadIdx.x & 63;   // local row
    const int f0 = threadIdx.x >> 6;   // 0..3
    for (int f = f0; f < FOUT; f += 4) {
        float s = 0.f;
        #pragma unroll 8
        for (int k = 0; k < FIN; ++k) s += sh[nl][k] * W[k * FOUT + f];
        __bf16 h = (__bf16)s;
        Tt[(size_t)f * NN + n0 + nl] = __builtin_bit_cast(unsigned short, h);
    }
}

// ---------------------------------------------------------------------------
// H = relu(adj @ T + b) with T given transposed in bf16: Tt [F, NN].
// F = NCB*16. grid: 256 blocks x 256 threads (4 waves); wave w of block g owns
// row block rb = 4*g + w (16 rows). MFMA 16x16x32 bf16; adj converted in-reg.
// ---------------------------------------------------------------------------
template<int NCB>
__global__ __launch_bounds__(256) void gc_kernel(
    const float* __restrict__ adj, const unsigned short* __restrict__ Tt,
    const float* __restrict__ bias, float* __restrict__ H)
{
    constexpr int F = NCB * 16;
    const int lane = threadIdx.x & 63;
    const int wave = threadIdx.x >> 6;
    const int rb   = blockIdx.x * 4 + wave;   // 0..1023
    const int m    = lane & 15;
    const int kq   = lane >> 4;               // 0..3

    const float* ap = adj + (size_t)(rb * 16 + m) * NN + kq * 8;
    const unsigned short* bp[NCB];
    f32x4 acc[NCB];
    #pragma unroll
    for (int cb = 0; cb < NCB; ++cb) {
        bp[cb] = Tt + (size_t)(cb * 16 + m) * NN + kq * 8;
        acc[cb] = (f32x4){0.f, 0.f, 0.f, 0.f};
    }

    #pragma unroll 4
    for (int kb = 0; kb < NN / 32; ++kb) {
        const f32x4* a4 = (const f32x4*)(ap + kb * 32);
        f32x4 a0 = a4[0];
        f32x4 a1 = a4[1];
        bf16x8 af = cvt_bf16x8(a0, a1);
        #pragma unroll
        for (int cb = 0; cb < NCB; ++cb) {
            bf16x8 bf = __builtin_bit_cast(bf16x8, *(const u16x8*)(bp[cb] + kb * 32));
            acc[cb] = __builtin_amdgcn_mfma_f32_16x16x32_bf16(af, bf, acc[cb], 0, 0, 0);
        }
    }

    // epilogue: C/D layout col = lane&15, row = (lane>>4)*4 + i
    #pragma unroll
    for (int cb = 0; cb < NCB; ++cb) {
        const int c = cb * 16 + m;
        const float bv = bias[c];
        #pragma unroll
        for (int i = 0; i < 4; ++i) {
            const int r = rb * 16 + kq * 4 + i;
            H[(size_t)r * F + c] = fmaxf(acc[cb][i] + bv, 0.f);
        }
    }
}

// ---------------------------------------------------------------------------
// Column partial sums of H3 [NN, 64] -> P [64 blocks][64 cols]
// ---------------------------------------------------------------------------
__global__ __launch_bounds__(256) void reduce_cols_kernel(
    const float* __restrict__ H3, float* __restrict__ P)
{
    __shared__ float sm[256];
    const int t = threadIdx.x;
    const int c = t & 63;
    const int rg = t >> 6;
    const int r0 = blockIdx.x * 256;
    float s = 0.f;
    #pragma unroll 4
    for (int j = 0; j < 64; ++j) {
        const int r = r0 + rg + j * 4;
        s += H3[(size_t)r * 64 + c];
    }
    sm[t] = s;
    __syncthreads();
    if (t < 64) P[blockIdx.x * 64 + t] = sm[t] + sm[t + 64] + sm[t + 128] + sm[t + 192];
}

// ---------------------------------------------------------------------------
// Head: y = mean -> relu(y@fcW1+fcb1) -> softmax(z@fcW2+fcb2). 1 block, 64 thr.
// ---------------------------------------------------------------------------
__global__ void head_kernel(
    const float* __restrict__ P,
    const float* __restrict__ fcW1, const float* __restrict__ fcb1,
    const float* __restrict__ fcW2, const float* __restrict__ fcb2,
    float* __restrict__ out)
{
    __shared__ float y[64];
    __shared__ float z1[32];
    __shared__ float lg[2];
    const int t = threadIdx.x;  // 0..63
    float s = 0.f;
    for (int w = 0; w < 64; ++w) s += P[w * 64 + t];
    y[t] = s * (1.0f / 16384.0f);
    __syncthreads();
    if (t < 32) {
        float a = fcb1[t];
        for (int k = 0; k < 64; ++k) a += y[k] * fcW1[k * 32 + t];
        z1[t] = fmaxf(a, 0.f);
    }
    __syncthreads();
    if (t < 2) {
        float a = fcb2[t];
        for (int j = 0; j < 32; ++j) a += z1[j] * fcW2[j * 2 + t];
        lg[t] = a;
    }
    __syncthreads();
    if (t == 0) {
        const float mx = fmaxf(lg[0], lg[1]);
        const float e0 = expf(lg[0] - mx), e1 = expf(lg[1] - mx);
        out[0] = e0 / (e0 + e1);
        out[1] = e1 / (e0 + e1);
    }
}

extern "C" void kernel_launch(void* const* d_in, const int* in_sizes, int n_in,
                              void* d_out, int out_size, void* d_ws, size_t ws_size,
                              hipStream_t stream) {
    const float* x     = (const float*)d_in[0];   // [NN,128]
    const float* adj   = (const float*)d_in[1];   // [NN,NN]
    // d_in[2] = idx_map (unused by reference)
    const float* W1    = (const float*)d_in[3];   // [128,32]
    const float* b1    = (const float*)d_in[4];
    const float* W2    = (const float*)d_in[5];   // [32,48]
    const float* b2    = (const float*)d_in[6];
    const float* W3    = (const float*)d_in[7];   // [48,64]
    const float* b3    = (const float*)d_in[8];
    const float* fcW1  = (const float*)d_in[9];   // [64,32]
    const float* fcb1  = (const float*)d_in[10];
    const float* fcW2  = (const float*)d_in[11];  // [32,2]
    const float* fcb2  = (const float*)d_in[12];
    float* out = (float*)d_out;

    char* ws = (char*)d_ws;
    unsigned short* Tt = (unsigned short*)(ws + 0);          // up to 64*NN bf16 = 2 MB
    float* H1 = (float*)(ws + (2u << 20));                   // NN*32 f32 = 2 MB
    float* H2 = (float*)(ws + (4u << 20));                   // NN*48 f32 = 3 MB
    float* H3 = (float*)(ws + (8u << 20));                   // NN*64 f32 = 4 MB
    float* P  = (float*)(ws + (12u << 20));                  // 64*64 f32

    // Layer 1: T = x@W1 ; H1 = relu(adj@T + b1)
    xw_t_kernel<128, 32><<<NN / 64, 256, 0, stream>>>(x, W1, Tt);
    gc_kernel<2><<<256, 256, 0, stream>>>(adj, Tt, b1, H1);
    // Layer 2
    xw_t_kernel<32, 48><<<NN / 64, 256, 0, stream>>>(H1, W2, Tt);
    gc_kernel<3><<<256, 256, 0, stream>>>(adj, Tt, b2, H2);
    // Layer 3
    xw_t_kernel<48, 64><<<NN / 64, 256, 0, stream>>>(H2, W3, Tt);
    gc_kernel<4><<<256, 256, 0, stream>>>(adj, Tt, b3, H3);
    // Readout + MLP head
    reduce_cols_kernel<<<64, 256, 0, stream>>>(H3, P);
    head_kernel<<<1, 64, 0, stream>>>(P, fcW1, fcb1, fcW2, fcb2, out);
}